// Round 4
// baseline (534.379 us; speedup 1.0000x reference)
//
#include <hip/hip_runtime.h>
#include <hip/hip_bf16.h>

#define NB 16
#define NT 512
#define ND 256
#define NH 4
#define NHD 64
#define NTAG 64

__device__ __forceinline__ float ldf(const void* p, int isbf, long i) {
  return isbf ? __bfloat162float(((const __hip_bfloat16*)p)[i])
              : ((const float*)p)[i];
}

template <int CTRL>
__device__ __forceinline__ float dppf(float v) {
  return __int_as_float(
      __builtin_amdgcn_update_dpp(0, __float_as_int(v), CTRL, 0xF, 0xF, false));
}

// ---------------- dtype detection + DPP direction probe ----------------
// flag[0]: 1 => inputs are bf16. flag[1]: 1 => row_ror:4 reads from lane+4.
__global__ void k_detect(const void* emb, int n, int* flag) {
  __shared__ int s_big;
  if (threadIdx.x == 0) s_big = 0;
  __syncthreads();
  const __hip_bfloat16* p = (const __hip_bfloat16*)emb;
  int big = 0;
  for (int i = threadIdx.x; i < n; i += blockDim.x) {
    float v = __bfloat162float(p[i]);
    if (fabsf(v) > 1e4f) big = 1;
  }
  if (big) atomicOr(&s_big, 1);
  int lane = threadIdx.x & 63;
  int r = __builtin_amdgcn_update_dpp(0, lane, 0x124, 0xF, 0xF, false); // row_ror:4
  if (threadIdx.x == 5) flag[1] = (r == 9) ? 1 : 0;
  __syncthreads();
  if (threadIdx.x == 0) *flag = s_big ? 0 : 1;
}

// ---------------- embedding gather ----------------
__global__ __launch_bounds__(64) void k_gather(const int* __restrict__ sent,
                                               const void* emb,
                                               float* __restrict__ X,
                                               const int* flagp) {
  int row = blockIdx.x;            // b*T + t
  int isbf = *flagp;
  long tok = (long)sent[row];
  long src = tok * ND;
  int d0 = threadIdx.x * 4;
  float4 r;
  r.x = ldf(emb, isbf, src + d0 + 0);
  r.y = ldf(emb, isbf, src + d0 + 1);
  r.z = ldf(emb, isbf, src + d0 + 2);
  r.w = ldf(emb, isbf, src + d0 + 3);
  *(float4*)&X[(long)row * ND + d0] = r;
}

// ---------------- GEMM: Y = X @ W^T + b ----------------
__global__ __launch_bounds__(256) void k_gemm(
    const float* __restrict__ A, const void* W0, const void* W1, const void* W2,
    const void* B0, const void* B1, const void* B2,
    float* O0, float* O1, float* O2, const int* flagp, int storeAttn) {
  __shared__ __align__(16) float As[16][68];
  __shared__ __align__(16) float Bs[16][68];
  int isbf = *flagp;
  int z = blockIdx.z;
  const void* W = (z == 0) ? W0 : (z == 1) ? W1 : W2;
  const void* Bb = (z == 0) ? B0 : (z == 1) ? B1 : B2;
  float* O = (z == 0) ? O0 : (z == 1) ? O1 : O2;

  int tid = threadIdx.x;
  int tx = tid & 15, ty = tid >> 4;
  int row0 = blockIdx.x * 64;
  int col0 = blockIdx.y * 64;

  float acc[4][4];
#pragma unroll
  for (int i = 0; i < 4; ++i)
#pragma unroll
    for (int j = 0; j < 4; ++j) acc[i][j] = 0.f;

  int r = tid >> 2;
  int kq = (tid & 3) << 2;

  for (int k0 = 0; k0 < 256; k0 += 16) {
    float4 a4 = *(const float4*)&A[(long)(row0 + r) * 256 + k0 + kq];
    As[kq + 0][r] = a4.x; As[kq + 1][r] = a4.y;
    As[kq + 2][r] = a4.z; As[kq + 3][r] = a4.w;
    long wb = (long)(col0 + r) * 256 + k0 + kq;
    Bs[kq + 0][r] = ldf(W, isbf, wb + 0);
    Bs[kq + 1][r] = ldf(W, isbf, wb + 1);
    Bs[kq + 2][r] = ldf(W, isbf, wb + 2);
    Bs[kq + 3][r] = ldf(W, isbf, wb + 3);
    __syncthreads();
#pragma unroll
    for (int kk = 0; kk < 16; ++kk) {
      float4 av4 = *(const float4*)&As[kk][ty * 4];
      float4 bv4 = *(const float4*)&Bs[kk][tx * 4];
      float av[4] = {av4.x, av4.y, av4.z, av4.w};
      float bv[4] = {bv4.x, bv4.y, bv4.z, bv4.w};
#pragma unroll
      for (int i = 0; i < 4; ++i)
#pragma unroll
        for (int j = 0; j < 4; ++j) acc[i][j] += av[i] * bv[j];
    }
    __syncthreads();
  }

  float bvv[4];
#pragma unroll
  for (int j = 0; j < 4; ++j) bvv[j] = ldf(Bb, isbf, col0 + tx * 4 + j);

#pragma unroll
  for (int i = 0; i < 4; ++i) {
    int row = row0 + ty * 4 + i;
    float4 r4;
    r4.x = acc[i][0] + bvv[0]; r4.y = acc[i][1] + bvv[1];
    r4.z = acc[i][2] + bvv[2]; r4.w = acc[i][3] + bvv[3];
    if (storeAttn) {
      int bb = row >> 9, tt = row & 511;
      *(float4*)&O[(((long)(bb * 4 + blockIdx.y)) * 512 + tt) * 64 + tx * 4] = r4;
    } else {
      *(float4*)&O[(long)row * 256 + col0 + tx * 4] = r4;
    }
  }
}

// ---------------- flash attention ----------------
__global__ __launch_bounds__(256) void k_attn(const float* __restrict__ Qg,
                                              const float* __restrict__ Kg,
                                              const float* __restrict__ Vg,
                                              float* __restrict__ AO) {
  __shared__ __align__(16) float Qs[64][68];
  __shared__ __align__(16) float KPs[64][68];
  __shared__ __align__(16) float Vs[64][68];
  int tid = threadIdx.x;
  int tx = tid & 15, ty = tid >> 4;
  int bh = blockIdx.x, qt = blockIdx.y;
  const float* Qb = Qg + ((long)bh * 512 + qt * 64) * 64;

#pragma unroll
  for (int c = 0; c < 4; ++c) {
    int idx = tid + c * 256;
    int m = idx >> 4, dq = (idx & 15) << 2;
    float4 q4 = *(const float4*)&Qb[m * 64 + dq];
    Qs[dq + 0][m] = q4.x; Qs[dq + 1][m] = q4.y;
    Qs[dq + 2][m] = q4.z; Qs[dq + 3][m] = q4.w;
  }

  float o[4][4];
  float mrow[4], lrow[4];
#pragma unroll
  for (int i = 0; i < 4; ++i) {
    mrow[i] = -1e30f; lrow[i] = 0.f;
#pragma unroll
    for (int j = 0; j < 4; ++j) o[i][j] = 0.f;
  }

  for (int kt = 0; kt < 8; ++kt) {
    __syncthreads();
    const float* Kb = Kg + ((long)bh * 512 + kt * 64) * 64;
    const float* Vb = Vg + ((long)bh * 512 + kt * 64) * 64;
#pragma unroll
    for (int c = 0; c < 4; ++c) {
      int idx = tid + c * 256;
      int n = idx >> 4, dq = (idx & 15) << 2;
      float4 k4 = *(const float4*)&Kb[n * 64 + dq];
      KPs[dq + 0][n] = k4.x; KPs[dq + 1][n] = k4.y;
      KPs[dq + 2][n] = k4.z; KPs[dq + 3][n] = k4.w;
      *(float4*)&Vs[n][dq] = *(const float4*)&Vb[n * 64 + dq];
    }
    __syncthreads();

    float s[4][4];
#pragma unroll
    for (int i = 0; i < 4; ++i)
#pragma unroll
      for (int j = 0; j < 4; ++j) s[i][j] = 0.f;
#pragma unroll 8
    for (int d = 0; d < 64; ++d) {
      float4 a4 = *(const float4*)&Qs[d][ty * 4];
      float4 b4 = *(const float4*)&KPs[d][tx * 4];
      float av[4] = {a4.x, a4.y, a4.z, a4.w};
      float bv[4] = {b4.x, b4.y, b4.z, b4.w};
#pragma unroll
      for (int i = 0; i < 4; ++i)
#pragma unroll
        for (int j = 0; j < 4; ++j) s[i][j] += av[i] * bv[j];
    }
#pragma unroll
    for (int i = 0; i < 4; ++i)
#pragma unroll
      for (int j = 0; j < 4; ++j) s[i][j] *= 0.125f;

    float rmax[4];
#pragma unroll
    for (int i = 0; i < 4; ++i)
      rmax[i] = fmaxf(fmaxf(s[i][0], s[i][1]), fmaxf(s[i][2], s[i][3]));
#pragma unroll
    for (int off = 1; off < 16; off <<= 1)
#pragma unroll
      for (int i = 0; i < 4; ++i)
        rmax[i] = fmaxf(rmax[i], __shfl_xor(rmax[i], off));

    float alpha[4], psum[4];
#pragma unroll
    for (int i = 0; i < 4; ++i) {
      float mnew = fmaxf(mrow[i], rmax[i]);
      alpha[i] = __expf(mrow[i] - mnew);
      mrow[i] = mnew;
      float ps = 0.f;
#pragma unroll
      for (int j = 0; j < 4; ++j) {
        s[i][j] = __expf(s[i][j] - mnew);
        ps += s[i][j];
      }
      psum[i] = ps;
    }
#pragma unroll
    for (int off = 1; off < 16; off <<= 1)
#pragma unroll
      for (int i = 0; i < 4; ++i) psum[i] += __shfl_xor(psum[i], off);
#pragma unroll
    for (int i = 0; i < 4; ++i) {
      lrow[i] = lrow[i] * alpha[i] + psum[i];
#pragma unroll
      for (int j = 0; j < 4; ++j) o[i][j] *= alpha[i];
    }

    __syncthreads();
#pragma unroll
    for (int i = 0; i < 4; ++i)
#pragma unroll
      for (int j = 0; j < 4; ++j) KPs[tx * 4 + j][ty * 4 + i] = s[i][j];
    __syncthreads();

#pragma unroll 8
    for (int n = 0; n < 64; ++n) {
      float4 p4 = *(const float4*)&KPs[n][ty * 4];
      float4 v4 = *(const float4*)&Vs[n][tx * 4];
      float pa[4] = {p4.x, p4.y, p4.z, p4.w};
      float va[4] = {v4.x, v4.y, v4.z, v4.w};
#pragma unroll
      for (int i = 0; i < 4; ++i)
#pragma unroll
        for (int j = 0; j < 4; ++j) o[i][j] += pa[i] * va[j];
    }
  }

  int b = bh >> 2, h = bh & 3;
#pragma unroll
  for (int i = 0; i < 4; ++i) {
    float inv = 1.f / lrow[i];
    int trow = qt * 64 + ty * 4 + i;
    float4 r4;
    r4.x = o[i][0] * inv; r4.y = o[i][1] * inv;
    r4.z = o[i][2] * inv; r4.w = o[i][3] * inv;
    *(float4*)&AO[((long)(b * 512 + trow)) * 256 + h * 64 + tx * 4] = r4;
  }
}

// ---------------- gate-angle precompute ----------------
// NEW layout: P2[x][t][64] with x = b>>2, col = (b&3)*16 + gate*4 + wire.
// Each scan block x reads a contiguous 128 KB slice.
__global__ __launch_bounds__(256) void k_precomp(
    const float* __restrict__ ATTN, const void* Wf, const void* Wi,
    const void* Wg, const void* Wo2, const void* bF, const void* bI,
    const void* bG, const void* bO, const void* thF, const void* thI,
    const void* thG, const void* thO, float* __restrict__ P,
    const int* flagp) {
  __shared__ __align__(16) float Xs[16][260];
  __shared__ float Ws[16][260];
  __shared__ float ab[16];
  int isbf = *flagp;
  int tid = threadIdx.x;
  int r0 = blockIdx.x * 16;

#pragma unroll
  for (int c = 0; c < 4; ++c) {
    int fi = tid + c * 256;
    int r = fi >> 6, dq = (fi & 63) << 2;
    *(float4*)&Xs[r][dq] = *(const float4*)&ATTN[(long)(r0 + r) * 256 + dq];
  }
  for (int e = tid; e < 4096; e += 256) {
    int out = e >> 8, k = e & 255;
    int gate = out >> 2, w = out & 3;
    const void* Wsel = (gate == 0) ? Wf : (gate == 1) ? Wi : (gate == 2) ? Wg : Wo2;
    Ws[out][k] = ldf(Wsel, isbf, (long)w * 260 + k);
  }
  if (tid < 16) {
    int gate = tid >> 2, w = tid & 3;
    const void* bsel = (gate == 0) ? bF : (gate == 1) ? bI : (gate == 2) ? bG : bO;
    const void* tsel = (gate == 0) ? thF : (gate == 1) ? thI : (gate == 2) ? thG : thO;
    ab[tid] = ldf(bsel, isbf, w) + ldf(tsel, isbf, w);
  }
  __syncthreads();

  int r = tid >> 4, oi = tid & 15;
  float acc = ab[oi];
#pragma unroll 8
  for (int k = 0; k < 256; ++k) acc += Xs[r][k] * Ws[oi][k];
  int rg = r0 + r;
  int b = rg >> 9, t = rg & 511;
  P[(long)(b >> 2) * 32768 + (long)t * 64 + (b & 3) * 16 + oi] = acc;
}

// ---------------- sequential scan: 4 blocks x 64 lanes ----------------
// lane = q*16 + G*4 + w. P streamed through a 2x8KB LDS double buffer in
// 32-step chunks: the single vmcnt drain per chunk lands ~6400 cyc after
// issue, so global latency is amortized to <30 cyc/step regardless of how
// the compiler places waits. Inner loop reads P from LDS (4-deep prefetch).
__global__ __launch_bounds__(64) void k_scan(const float* __restrict__ P,
                                             const void* Wf, const void* Wi,
                                             const void* Wg, const void* Wo2,
                                             float* __restrict__ HS,
                                             const int* flagp) {
  __shared__ __align__(16) float pb[2][2048];   // 2 x 8KB P chunks (32 t each)
  __shared__ __align__(16) float hsb[512 * 16]; // h history, dumped at end
  int lane = threadIdx.x;
  int q = lane >> 4, G = (lane >> 2) & 3, w = lane & 3;
  int isbf = flagp[0];
  int dir = flagp[1];  // 1 => row_ror:4 reads lane+4 (gate G+1)
  const void* Wsel = (G == 0) ? Wf : (G == 1) ? Wi : (G == 2) ? Wg : Wo2;
  float r0 = ldf(Wsel, isbf, (long)w * 260 + 256 + 0);
  float r1 = ldf(Wsel, isbf, (long)w * 260 + 256 + 1);
  float r2 = ldf(Wsel, isbf, (long)w * 260 + 256 + 2);
  float r3 = ldf(Wsel, isbf, (long)w * 260 + 256 + 3);
  float kk = (G == 2) ? 2.f : 1.f;   // gate g uses tanh = 2*sigmoid(2x)-1
  float km1 = kk - 1.f;
  int s0 = (0 - G) & 3, s1 = (1 - G) & 3, s2 = (2 - G) & 3, s3 = (3 - G) & 3;
  float h0 = 0.f, h1 = 0.f, h2 = 0.f, h3 = 0.f, cx = 0.f;
  int hoff = q * 4 + w;

  const float4* Pq = (const float4*)(P + (long)blockIdx.x * 32768);
  float4 stage[8];
  // chunk 0 -> regs -> pb[0]
#pragma unroll
  for (int j = 0; j < 8; ++j) stage[j] = Pq[j * 64 + lane];
#pragma unroll
  for (int j = 0; j < 8; ++j)
    *(float4*)&pb[0][(j * 64 + lane) * 4] = stage[j];
  // issue chunk 1 loads (consumed 32 steps from now)
#pragma unroll
  for (int j = 0; j < 8; ++j) stage[j] = Pq[512 + j * 64 + lane];

  for (int ck = 0; ck < 16; ++ck) {
    const float* cur = pb[ck & 1];
    float lbuf[4];
#pragma unroll
    for (int j = 0; j < 4; ++j) lbuf[j] = cur[j * 64 + lane];
    int tbase = ck * 32;
    for (int tl = 0; tl < 32; tl += 4) {
#pragma unroll
      for (int u = 0; u < 4; ++u) {
        int t = tbase + tl + u;
        float pc = lbuf[u];
        lbuf[u] = cur[((tl + u + 4) & 31) * 64 + lane];  // wrapped; dead at tail
        float a = pc + r0 * h0 + r1 * h1 + r2 * h2 + r3 * h3;
        float c = __cosf(a);
        float c0 = dppf<0x00>(c), c1 = dppf<0x55>(c);
        float c2 = dppf<0xAA>(c), c3 = dppf<0xFF>(c);
        float p01 = c0 * c1, z23 = c2 * c3;
        float v = (w == 0) ? c1 * z23 : (w == 1) ? p01
                : (w == 2) ? p01 * c2 : p01 * z23;
        float val = kk / (1.f + __expf(-kk * v)) - km1;
        float ra = dppf<0x124>(val);   // row_ror:4
        float rb = dppf<0x128>(val);   // row_ror:8
        float rc = dppf<0x12C>(val);   // row_ror:12
        float rot1 = dir ? ra : rc;
        float rot3 = dir ? rc : ra;
        float f = (s0 == 0) ? val : (s0 == 1) ? rot1 : (s0 == 2) ? rb : rot3;
        float i = (s1 == 0) ? val : (s1 == 1) ? rot1 : (s1 == 2) ? rb : rot3;
        float g = (s2 == 0) ? val : (s2 == 1) ? rot1 : (s2 == 2) ? rb : rot3;
        float o = (s3 == 0) ? val : (s3 == 1) ? rot1 : (s3 == 2) ? rb : rot3;
        cx = f * cx + i * g;
        float th = 2.f / (1.f + __expf(-2.f * cx)) - 1.f;
        float hx = o * th;
        h0 = dppf<0x00>(hx); h1 = dppf<0x55>(hx);
        h2 = dppf<0xAA>(hx); h3 = dppf<0xFF>(hx);
        if (G == 0) hsb[t * 16 + hoff] = hx;
      }
    }
    if (ck < 15) {
      // commit staged chunk ck+1 (vmcnt wait lands here, 32 steps post-issue)
#pragma unroll
      for (int j = 0; j < 8; ++j)
        *(float4*)&pb[(ck + 1) & 1][(j * 64 + lane) * 4] = stage[j];
      if (ck < 14) {
#pragma unroll
        for (int j = 0; j < 8; ++j)
          stage[j] = Pq[(ck + 2) * 512 + j * 64 + lane];
      }
    }
  }
  int hb = blockIdx.x * 16;
#pragma unroll
  for (int i4 = 0; i4 < 32; ++i4) {
    int fi = (i4 * 64 + lane) * 4;       // float index, 16B aligned
    int t = fi >> 4, j = fi & 15;
    *(float4*)&HS[t * 64 + hb + j] = *(const float4*)&hsb[fi];
  }
}

// ---------------- logits + log_softmax ----------------
__global__ __launch_bounds__(64) void k_final(const float* __restrict__ HS,
                                              const void* Wt, const void* Bt,
                                              void* outp, const int* flagp) {
  int r = blockIdx.x;
  int b = r >> 9, t = r & 511;
  int j = threadIdx.x;
  int isbf = *flagp;
  const float* h = &HS[t * 64 + b * 4];
  float h0 = h[0], h1 = h[1], h2 = h[2], h3 = h[3];
  float lg = ldf(Bt, isbf, j)
           + h0 * ldf(Wt, isbf, (long)j * 4 + 0)
           + h1 * ldf(Wt, isbf, (long)j * 4 + 1)
           + h2 * ldf(Wt, isbf, (long)j * 4 + 2)
           + h3 * ldf(Wt, isbf, (long)j * 4 + 3);
  float mx = lg;
#pragma unroll
  for (int off = 1; off < 64; off <<= 1) mx = fmaxf(mx, __shfl_xor(mx, off));
  float e = __expf(lg - mx);
  float ssum = e;
#pragma unroll
  for (int off = 1; off < 64; off <<= 1) ssum += __shfl_xor(ssum, off);
  float res = lg - mx - __logf(ssum);
  long oidx = (long)r * 64 + j;
  if (isbf) ((__hip_bfloat16*)outp)[oidx] = __float2bfloat16(res);
  else ((float*)outp)[oidx] = res;
}

extern "C" void kernel_launch(void* const* d_in, const int* in_sizes, int n_in,
                              void* d_out, int out_size, void* d_ws, size_t ws_size,
                              hipStream_t stream) {
  const int* sent = (const int*)d_in[0];
  const void* emb = d_in[1];
  const void* Wq = d_in[2];  const void* bq = d_in[3];
  const void* Wk = d_in[4];  const void* bk = d_in[5];
  const void* Wv = d_in[6];  const void* bv = d_in[7];
  const void* Wo = d_in[8];  const void* bo = d_in[9];
  const void* Wf = d_in[10]; const void* bF = d_in[11]; const void* thF = d_in[12];
  const void* Wi = d_in[13]; const void* bI = d_in[14]; const void* thI = d_in[15];
  const void* Wg = d_in[16]; const void* bG = d_in[17]; const void* thG = d_in[18];
  const void* Wo2 = d_in[19]; const void* bO = d_in[20]; const void* thO = d_in[21];
  const void* Wt = d_in[22]; const void* Bt = d_in[23];

  int* flag = (int*)d_ws;
  float* base = (float*)((char*)d_ws + 256);
  float* X  = base;                 // 2M floats; later reused as AO
  float* Qb = X + 2097152;          // later reused as ATTN
  float* Kb = Qb + 2097152;
  float* Vb = Kb + 2097152;
  float* Pp = Vb + 2097152;         // 131072 floats (4 x 32768 block-major)
  float* HS = Pp + 131072;          // 32768 floats

  k_detect<<<1, 256, 0, stream>>>(emb, 32768, flag);
  k_gather<<<8192, 64, 0, stream>>>(sent, emb, X, flag);
  dim3 gq(128, 4, 3);
  k_gemm<<<gq, 256, 0, stream>>>(X, Wq, Wk, Wv, bq, bk, bv, Qb, Kb, Vb, flag, 1);
  dim3 ga(64, 8, 1);
  k_attn<<<ga, 256, 0, stream>>>(Qb, Kb, Vb, X);     // AO -> X buffer
  dim3 gw(128, 4, 1);
  k_gemm<<<gw, 256, 0, stream>>>(X, Wo, Wo, Wo, bo, bo, bo, Qb, Qb, Qb, flag, 0);
  k_precomp<<<512, 256, 0, stream>>>(Qb, Wf, Wi, Wg, Wo2, bF, bI, bG, bO,
                                     thF, thI, thG, thO, Pp, flag);
  k_scan<<<4, 64, 0, stream>>>(Pp, Wf, Wi, Wg, Wo2, HS, flag);
  k_final<<<8192, 64, 0, stream>>>(HS, Wt, Bt, d_out, flag);
}

// Round 5
// 458.269 us; speedup vs baseline: 1.1661x; 1.1661x over previous
//
#include <hip/hip_runtime.h>
#include <hip/hip_bf16.h>

#define NB 16
#define NT 512
#define ND 256
#define NH 4
#define NHD 64
#define NTAG 64

typedef short bf16x8 __attribute__((ext_vector_type(8)));
typedef float f32x4 __attribute__((ext_vector_type(4)));
union LdsVec { uint4 u; bf16x8 v; };

__device__ __forceinline__ float ldf(const void* p, int isbf, long i) {
  return isbf ? __bfloat162float(((const __hip_bfloat16*)p)[i])
              : ((const float*)p)[i];
}
__device__ __forceinline__ unsigned short bfbits(float f) {
  __hip_bfloat16 h = __float2bfloat16(f);
  union { __hip_bfloat16 h; unsigned short s; } u{h};
  return u.s;
}
__device__ __forceinline__ unsigned int pack2(float a, float b) {
  return ((unsigned int)bfbits(b) << 16) | bfbits(a);
}

template <int CTRL>
__device__ __forceinline__ float dppf(float v) {
  return __int_as_float(
      __builtin_amdgcn_update_dpp(0, __float_as_int(v), CTRL, 0xF, 0xF, false));
}

// ---------------- dtype detection + DPP direction probe ----------------
__global__ void k_detect(const void* emb, int n, int* flag) {
  __shared__ int s_big;
  if (threadIdx.x == 0) s_big = 0;
  __syncthreads();
  const __hip_bfloat16* p = (const __hip_bfloat16*)emb;
  int big = 0;
  for (int i = threadIdx.x; i < n; i += blockDim.x) {
    float v = __bfloat162float(p[i]);
    if (fabsf(v) > 1e4f) big = 1;
  }
  if (big) atomicOr(&s_big, 1);
  int lane = threadIdx.x & 63;
  int r = __builtin_amdgcn_update_dpp(0, lane, 0x124, 0xF, 0xF, false); // row_ror:4
  if (threadIdx.x == 5) flag[1] = (r == 9) ? 1 : 0;
  __syncthreads();
  if (threadIdx.x == 0) *flag = s_big ? 0 : 1;
}

// ---------------- embedding gather (emit bf16 X) ----------------
__global__ __launch_bounds__(64) void k_gather(const int* __restrict__ sent,
                                               const void* emb,
                                               __hip_bfloat16* __restrict__ X,
                                               const int* flagp) {
  int row = blockIdx.x;            // b*T + t
  int isbf = *flagp;
  long tok = (long)sent[row];
  long src = tok * ND;
  int d0 = threadIdx.x * 4;
  uint2 packed;
  packed.x = pack2(ldf(emb, isbf, src + d0 + 0), ldf(emb, isbf, src + d0 + 1));
  packed.y = pack2(ldf(emb, isbf, src + d0 + 2), ldf(emb, isbf, src + d0 + 3));
  *(uint2*)&X[(long)row * ND + d0] = packed;
}

// ---------------- MFMA GEMM: Y = Xbf @ W^T + b ----------------
// M=8192 (128 tiles of 64), N=256 (4 tiles of 64), K=256 (8 steps of 32).
// 256 threads = 4 waves; wave w computes 32x32 via 2x2 mfma_f32_16x16x32_bf16.
__global__ __launch_bounds__(256) void k_gemm(
    const __hip_bfloat16* __restrict__ A, const void* W0, const void* W1,
    const void* W2, const void* B0, const void* B1, const void* B2,
    float* O0, float* O1, float* O2, const int* flagp, int storeAttn) {
  __shared__ __align__(16) unsigned short Abuf[64 * 32];
  __shared__ __align__(16) unsigned short Bbuf[64 * 32];
  int isbf = *flagp;
  int z = blockIdx.z;
  const void* W = (z == 0) ? W0 : (z == 1) ? W1 : W2;
  const void* Bb = (z == 0) ? B0 : (z == 1) ? B1 : B2;
  float* O = (z == 0) ? O0 : (z == 1) ? O1 : O2;

  int tid = threadIdx.x;
  int rowbase = blockIdx.x * 64;
  int colbase = blockIdx.y * 64;
  int srow = tid >> 2;             // 0..63
  int skq = (tid & 3) * 8;         // 0,8,16,24

  int wave = tid >> 6, lane = tid & 63;
  int li = lane & 15, quad = lane >> 4;
  int msub = (wave & 1) * 32, nsub = (wave >> 1) * 32;

  f32x4 acc[2][2];
#pragma unroll
  for (int i = 0; i < 2; ++i)
#pragma unroll
    for (int j = 0; j < 2; ++j) acc[i][j] = (f32x4){0.f, 0.f, 0.f, 0.f};

  for (int k0 = 0; k0 < 256; k0 += 32) {
    // stage A tile (already bf16): 8 contiguous bf16 = uint4
    *(uint4*)&Abuf[srow * 32 + skq] =
        *(const uint4*)&A[(long)(rowbase + srow) * 256 + k0 + skq];
    // stage B tile = W rows (convert if f32)
    long wb = (long)(colbase + srow) * 256 + k0 + skq;
    if (isbf) {
      *(uint4*)&Bbuf[srow * 32 + skq] = *(const uint4*)((const __hip_bfloat16*)W + wb);
    } else {
      const float* Wf = (const float*)W + wb;
      float4 lo = *(const float4*)Wf;
      float4 hi = *(const float4*)(Wf + 4);
      uint4 pk;
      pk.x = pack2(lo.x, lo.y); pk.y = pack2(lo.z, lo.w);
      pk.z = pack2(hi.x, hi.y); pk.w = pack2(hi.z, hi.w);
      *(uint4*)&Bbuf[srow * 32 + skq] = pk;
    }
    __syncthreads();

    LdsVec a0, a1, b0, b1;
    a0.u = *(const uint4*)&Abuf[(msub + li) * 32 + quad * 8];
    a1.u = *(const uint4*)&Abuf[(msub + 16 + li) * 32 + quad * 8];
    b0.u = *(const uint4*)&Bbuf[(nsub + li) * 32 + quad * 8];
    b1.u = *(const uint4*)&Bbuf[(nsub + 16 + li) * 32 + quad * 8];
    acc[0][0] = __builtin_amdgcn_mfma_f32_16x16x32_bf16(a0.v, b0.v, acc[0][0], 0, 0, 0);
    acc[0][1] = __builtin_amdgcn_mfma_f32_16x16x32_bf16(a0.v, b1.v, acc[0][1], 0, 0, 0);
    acc[1][0] = __builtin_amdgcn_mfma_f32_16x16x32_bf16(a1.v, b0.v, acc[1][0], 0, 0, 0);
    acc[1][1] = __builtin_amdgcn_mfma_f32_16x16x32_bf16(a1.v, b1.v, acc[1][1], 0, 0, 0);
    __syncthreads();
  }

#pragma unroll
  for (int nt = 0; nt < 2; ++nt) {
    int col = colbase + nsub + nt * 16 + li;
    float bias = ldf(Bb, isbf, col);
#pragma unroll
    for (int mt = 0; mt < 2; ++mt) {
#pragma unroll
      for (int reg = 0; reg < 4; ++reg) {
        int row = rowbase + msub + mt * 16 + quad * 4 + reg;
        float v = acc[mt][nt][reg] + bias;
        if (storeAttn) {
          int bb = row >> 9, tt = row & 511;
          int h = col >> 6, hd = col & 63;
          O[(((long)(bb * 4 + h)) * 512 + tt) * 64 + hd] = v;
        } else {
          O[(long)row * 256 + col] = v;
        }
      }
    }
  }
}

// ---------------- flash attention (f32; emits bf16 AO) ----------------
__global__ __launch_bounds__(256) void k_attn(const float* __restrict__ Qg,
                                              const float* __restrict__ Kg,
                                              const float* __restrict__ Vg,
                                              __hip_bfloat16* __restrict__ AO) {
  __shared__ __align__(16) float Qs[64][68];
  __shared__ __align__(16) float KPs[64][68];
  __shared__ __align__(16) float Vs[64][68];
  int tid = threadIdx.x;
  int tx = tid & 15, ty = tid >> 4;
  int bh = blockIdx.x, qt = blockIdx.y;
  const float* Qb = Qg + ((long)bh * 512 + qt * 64) * 64;

#pragma unroll
  for (int c = 0; c < 4; ++c) {
    int idx = tid + c * 256;
    int m = idx >> 4, dq = (idx & 15) << 2;
    float4 q4 = *(const float4*)&Qb[m * 64 + dq];
    Qs[dq + 0][m] = q4.x; Qs[dq + 1][m] = q4.y;
    Qs[dq + 2][m] = q4.z; Qs[dq + 3][m] = q4.w;
  }

  float o[4][4];
  float mrow[4], lrow[4];
#pragma unroll
  for (int i = 0; i < 4; ++i) {
    mrow[i] = -1e30f; lrow[i] = 0.f;
#pragma unroll
    for (int j = 0; j < 4; ++j) o[i][j] = 0.f;
  }

  for (int kt = 0; kt < 8; ++kt) {
    __syncthreads();
    const float* Kb = Kg + ((long)bh * 512 + kt * 64) * 64;
    const float* Vb = Vg + ((long)bh * 512 + kt * 64) * 64;
#pragma unroll
    for (int c = 0; c < 4; ++c) {
      int idx = tid + c * 256;
      int n = idx >> 4, dq = (idx & 15) << 2;
      float4 k4 = *(const float4*)&Kb[n * 64 + dq];
      KPs[dq + 0][n] = k4.x; KPs[dq + 1][n] = k4.y;
      KPs[dq + 2][n] = k4.z; KPs[dq + 3][n] = k4.w;
      *(float4*)&Vs[n][dq] = *(const float4*)&Vb[n * 64 + dq];
    }
    __syncthreads();

    float s[4][4];
#pragma unroll
    for (int i = 0; i < 4; ++i)
#pragma unroll
      for (int j = 0; j < 4; ++j) s[i][j] = 0.f;
#pragma unroll 8
    for (int d = 0; d < 64; ++d) {
      float4 a4 = *(const float4*)&Qs[d][ty * 4];
      float4 b4 = *(const float4*)&KPs[d][tx * 4];
      float av[4] = {a4.x, a4.y, a4.z, a4.w};
      float bv[4] = {b4.x, b4.y, b4.z, b4.w};
#pragma unroll
      for (int i = 0; i < 4; ++i)
#pragma unroll
        for (int j = 0; j < 4; ++j) s[i][j] += av[i] * bv[j];
    }
#pragma unroll
    for (int i = 0; i < 4; ++i)
#pragma unroll
      for (int j = 0; j < 4; ++j) s[i][j] *= 0.125f;

    float rmax[4];
#pragma unroll
    for (int i = 0; i < 4; ++i)
      rmax[i] = fmaxf(fmaxf(s[i][0], s[i][1]), fmaxf(s[i][2], s[i][3]));
#pragma unroll
    for (int off = 1; off < 16; off <<= 1)
#pragma unroll
      for (int i = 0; i < 4; ++i)
        rmax[i] = fmaxf(rmax[i], __shfl_xor(rmax[i], off));

    float alpha[4], psum[4];
#pragma unroll
    for (int i = 0; i < 4; ++i) {
      float mnew = fmaxf(mrow[i], rmax[i]);
      alpha[i] = __expf(mrow[i] - mnew);
      mrow[i] = mnew;
      float ps = 0.f;
#pragma unroll
      for (int j = 0; j < 4; ++j) {
        s[i][j] = __expf(s[i][j] - mnew);
        ps += s[i][j];
      }
      psum[i] = ps;
    }
#pragma unroll
    for (int off = 1; off < 16; off <<= 1)
#pragma unroll
      for (int i = 0; i < 4; ++i) psum[i] += __shfl_xor(psum[i], off);
#pragma unroll
    for (int i = 0; i < 4; ++i) {
      lrow[i] = lrow[i] * alpha[i] + psum[i];
#pragma unroll
      for (int j = 0; j < 4; ++j) o[i][j] *= alpha[i];
    }

    __syncthreads();
#pragma unroll
    for (int i = 0; i < 4; ++i)
#pragma unroll
      for (int j = 0; j < 4; ++j) KPs[tx * 4 + j][ty * 4 + i] = s[i][j];
    __syncthreads();

#pragma unroll 8
    for (int n = 0; n < 64; ++n) {
      float4 p4 = *(const float4*)&KPs[n][ty * 4];
      float4 v4 = *(const float4*)&Vs[n][tx * 4];
      float pa[4] = {p4.x, p4.y, p4.z, p4.w};
      float va[4] = {v4.x, v4.y, v4.z, v4.w};
#pragma unroll
      for (int i = 0; i < 4; ++i)
#pragma unroll
        for (int j = 0; j < 4; ++j) o[i][j] += pa[i] * va[j];
    }
  }

  int b = bh >> 2, h = bh & 3;
#pragma unroll
  for (int i = 0; i < 4; ++i) {
    float inv = 1.f / lrow[i];
    int trow = qt * 64 + ty * 4 + i;
    uint2 pk;
    pk.x = pack2(o[i][0] * inv, o[i][1] * inv);
    pk.y = pack2(o[i][2] * inv, o[i][3] * inv);
    *(uint2*)&AO[((long)(b * 512 + trow)) * 256 + h * 64 + tx * 4] = pk;
  }
}

// ---------------- gate-angle precompute ----------------
// P2[x][t][64] with x = b>>2, col = (b&3)*16 + gate*4 + wire.
__global__ __launch_bounds__(256) void k_precomp(
    const float* __restrict__ ATTN, const void* Wf, const void* Wi,
    const void* Wg, const void* Wo2, const void* bF, const void* bI,
    const void* bG, const void* bO, const void* thF, const void* thI,
    const void* thG, const void* thO, float* __restrict__ P,
    const int* flagp) {
  __shared__ __align__(16) float Xs[16][260];
  __shared__ float Ws[16][260];
  __shared__ float ab[16];
  int isbf = *flagp;
  int tid = threadIdx.x;
  int r0 = blockIdx.x * 16;

#pragma unroll
  for (int c = 0; c < 4; ++c) {
    int fi = tid + c * 256;
    int r = fi >> 6, dq = (fi & 63) << 2;
    *(float4*)&Xs[r][dq] = *(const float4*)&ATTN[(long)(r0 + r) * 256 + dq];
  }
  for (int e = tid; e < 4096; e += 256) {
    int out = e >> 8, k = e & 255;
    int gate = out >> 2, w = out & 3;
    const void* Wsel = (gate == 0) ? Wf : (gate == 1) ? Wi : (gate == 2) ? Wg : Wo2;
    Ws[out][k] = ldf(Wsel, isbf, (long)w * 260 + k);
  }
  if (tid < 16) {
    int gate = tid >> 2, w = tid & 3;
    const void* bsel = (gate == 0) ? bF : (gate == 1) ? bI : (gate == 2) ? bG : bO;
    const void* tsel = (gate == 0) ? thF : (gate == 1) ? thI : (gate == 2) ? thG : thO;
    ab[tid] = ldf(bsel, isbf, w) + ldf(tsel, isbf, w);
  }
  __syncthreads();

  int r = tid >> 4, oi = tid & 15;
  float acc = ab[oi];
#pragma unroll 8
  for (int k = 0; k < 256; ++k) acc += Xs[r][k] * Ws[oi][k];
  int rg = r0 + r;
  int b = rg >> 9, t = rg & 511;
  P[(long)(b >> 2) * 32768 + (long)t * 64 + (b & 3) * 16 + oi] = acc;
}

// ---------------- sequential scan: 4 blocks x 64 lanes ----------------
__global__ __launch_bounds__(64) void k_scan(const float* __restrict__ P,
                                             const void* Wf, const void* Wi,
                                             const void* Wg, const void* Wo2,
                                             float* __restrict__ HS,
                                             const int* flagp) {
  __shared__ __align__(16) float pb[2][2048];   // 2 x 8KB P chunks (32 t each)
  __shared__ __align__(16) float hsb[512 * 16]; // h history, dumped at end
  int lane = threadIdx.x;
  int q = lane >> 4, G = (lane >> 2) & 3, w = lane & 3;
  int isbf = flagp[0];
  int dir = flagp[1];
  const void* Wsel = (G == 0) ? Wf : (G == 1) ? Wi : (G == 2) ? Wg : Wo2;
  float r0 = ldf(Wsel, isbf, (long)w * 260 + 256 + 0);
  float r1 = ldf(Wsel, isbf, (long)w * 260 + 256 + 1);
  float r2 = ldf(Wsel, isbf, (long)w * 260 + 256 + 2);
  float r3 = ldf(Wsel, isbf, (long)w * 260 + 256 + 3);
  float kk = (G == 2) ? 2.f : 1.f;
  float km1 = kk - 1.f;
  int s0 = (0 - G) & 3, s1 = (1 - G) & 3, s2 = (2 - G) & 3, s3 = (3 - G) & 3;
  float h0 = 0.f, h1 = 0.f, h2 = 0.f, h3 = 0.f, cx = 0.f;
  int hoff = q * 4 + w;

  const float4* Pq = (const float4*)(P + (long)blockIdx.x * 32768);
  float4 stage[8];
#pragma unroll
  for (int j = 0; j < 8; ++j) stage[j] = Pq[j * 64 + lane];
#pragma unroll
  for (int j = 0; j < 8; ++j)
    *(float4*)&pb[0][(j * 64 + lane) * 4] = stage[j];
#pragma unroll
  for (int j = 0; j < 8; ++j) stage[j] = Pq[512 + j * 64 + lane];

  for (int ck = 0; ck < 16; ++ck) {
    const float* cur = pb[ck & 1];
    float lbuf[4];
#pragma unroll
    for (int j = 0; j < 4; ++j) lbuf[j] = cur[j * 64 + lane];
    int tbase = ck * 32;
    for (int tl = 0; tl < 32; tl += 4) {
#pragma unroll
      for (int u = 0; u < 4; ++u) {
        int t = tbase + tl + u;
        float pc = lbuf[u];
        lbuf[u] = cur[((tl + u + 4) & 31) * 64 + lane];
        float a = pc + r0 * h0 + r1 * h1 + r2 * h2 + r3 * h3;
        float c = __cosf(a);
        float c0 = dppf<0x00>(c), c1 = dppf<0x55>(c);
        float c2 = dppf<0xAA>(c), c3 = dppf<0xFF>(c);
        float p01 = c0 * c1, z23 = c2 * c3;
        float v = (w == 0) ? c1 * z23 : (w == 1) ? p01
                : (w == 2) ? p01 * c2 : p01 * z23;
        float val = kk / (1.f + __expf(-kk * v)) - km1;
        float ra = dppf<0x124>(val);
        float rb = dppf<0x128>(val);
        float rc = dppf<0x12C>(val);
        float rot1 = dir ? ra : rc;
        float rot3 = dir ? rc : ra;
        float f = (s0 == 0) ? val : (s0 == 1) ? rot1 : (s0 == 2) ? rb : rot3;
        float i = (s1 == 0) ? val : (s1 == 1) ? rot1 : (s1 == 2) ? rb : rot3;
        float g = (s2 == 0) ? val : (s2 == 1) ? rot1 : (s2 == 2) ? rb : rot3;
        float o = (s3 == 0) ? val : (s3 == 1) ? rot1 : (s3 == 2) ? rb : rot3;
        cx = f * cx + i * g;
        float th = 2.f / (1.f + __expf(-2.f * cx)) - 1.f;
        float hx = o * th;
        h0 = dppf<0x00>(hx); h1 = dppf<0x55>(hx);
        h2 = dppf<0xAA>(hx); h3 = dppf<0xFF>(hx);
        if (G == 0) hsb[t * 16 + hoff] = hx;
      }
    }
    if (ck < 15) {
#pragma unroll
      for (int j = 0; j < 8; ++j)
        *(float4*)&pb[(ck + 1) & 1][(j * 64 + lane) * 4] = stage[j];
      if (ck < 14) {
#pragma unroll
        for (int j = 0; j < 8; ++j)
          stage[j] = Pq[(ck + 2) * 512 + j * 64 + lane];
      }
    }
  }
  int hb = blockIdx.x * 16;
#pragma unroll
  for (int i4 = 0; i4 < 32; ++i4) {
    int fi = (i4 * 64 + lane) * 4;
    int t = fi >> 4, j = fi & 15;
    *(float4*)&HS[t * 64 + hb + j] = *(const float4*)&hsb[fi];
  }
}

// ---------------- logits + log_softmax ----------------
__global__ __launch_bounds__(64) void k_final(const float* __restrict__ HS,
                                              const void* Wt, const void* Bt,
                                              void* outp, const int* flagp) {
  int r = blockIdx.x;
  int b = r >> 9, t = r & 511;
  int j = threadIdx.x;
  int isbf = *flagp;
  const float* h = &HS[t * 64 + b * 4];
  float h0 = h[0], h1 = h[1], h2 = h[2], h3 = h[3];
  float lg = ldf(Bt, isbf, j)
           + h0 * ldf(Wt, isbf, (long)j * 4 + 0)
           + h1 * ldf(Wt, isbf, (long)j * 4 + 1)
           + h2 * ldf(Wt, isbf, (long)j * 4 + 2)
           + h3 * ldf(Wt, isbf, (long)j * 4 + 3);
  float mx = lg;
#pragma unroll
  for (int off = 1; off < 64; off <<= 1) mx = fmaxf(mx, __shfl_xor(mx, off));
  float e = __expf(lg - mx);
  float ssum = e;
#pragma unroll
  for (int off = 1; off < 64; off <<= 1) ssum += __shfl_xor(ssum, off);
  float res = lg - mx - __logf(ssum);
  long oidx = (long)r * 64 + j;
  if (isbf) ((__hip_bfloat16*)outp)[oidx] = __float2bfloat16(res);
  else ((float*)outp)[oidx] = res;
}

extern "C" void kernel_launch(void* const* d_in, const int* in_sizes, int n_in,
                              void* d_out, int out_size, void* d_ws, size_t ws_size,
                              hipStream_t stream) {
  const int* sent = (const int*)d_in[0];
  const void* emb = d_in[1];
  const void* Wq = d_in[2];  const void* bq = d_in[3];
  const void* Wk = d_in[4];  const void* bk = d_in[5];
  const void* Wv = d_in[6];  const void* bv = d_in[7];
  const void* Wo = d_in[8];  const void* bo = d_in[9];
  const void* Wf = d_in[10]; const void* bF = d_in[11]; const void* thF = d_in[12];
  const void* Wi = d_in[13]; const void* bI = d_in[14]; const void* thI = d_in[15];
  const void* Wg = d_in[16]; const void* bG = d_in[17]; const void* thG = d_in[18];
  const void* Wo2 = d_in[19]; const void* bO = d_in[20]; const void* thO = d_in[21];
  const void* Wt = d_in[22]; const void* Bt = d_in[23];

  int* flag = (int*)d_ws;
  float* base = (float*)((char*)d_ws + 256);
  __hip_bfloat16* Xbf = (__hip_bfloat16*)base;  // 8192x256 bf16 (4MB); reused as AO
  float* Qb = base + 2097152;       // f32 Q; later reused as ATTN
  float* Kb = Qb + 2097152;
  float* Vb = Kb + 2097152;
  float* Pp = Vb + 2097152;         // 131072 floats (4 x 32768 block-major)
  float* HS = Pp + 131072;          // 32768 floats

  k_detect<<<1, 256, 0, stream>>>(emb, 32768, flag);
  k_gather<<<8192, 64, 0, stream>>>(sent, emb, Xbf, flag);
  dim3 gq(128, 4, 3);
  k_gemm<<<gq, 256, 0, stream>>>(Xbf, Wq, Wk, Wv, bq, bk, bv, Qb, Kb, Vb, flag, 1);
  dim3 ga(64, 8, 1);
  k_attn<<<ga, 256, 0, stream>>>(Qb, Kb, Vb, Xbf);   // AO (bf16) -> Xbf
  dim3 gw(128, 4, 1);
  k_gemm<<<gw, 256, 0, stream>>>(Xbf, Wo, Wo, Wo, bo, bo, bo, Qb, Qb, Qb, flag, 0);
  k_precomp<<<512, 256, 0, stream>>>(Qb, Wf, Wi, Wg, Wo2, bF, bI, bG, bO,
                                     thF, thI, thG, thO, Pp, flag);
  k_scan<<<4, 64, 0, stream>>>(Pp, Wf, Wi, Wg, Wo2, HS, flag);
  k_final<<<8192, 64, 0, stream>>>(HS, Wt, Bt, d_out, flag);
}

// Round 6
// 400.994 us; speedup vs baseline: 1.3326x; 1.1428x over previous
//
#include <hip/hip_runtime.h>
#include <hip/hip_bf16.h>

#define NB 16
#define NT 512
#define ND 256
#define NH 4
#define NHD 64
#define NTAG 64

typedef short bf16x8 __attribute__((ext_vector_type(8)));
typedef float f32x4 __attribute__((ext_vector_type(4)));
union LdsVec { uint4 u; bf16x8 v; };

__device__ __forceinline__ float ldf(const void* p, int isbf, long i) {
  return isbf ? __bfloat162float(((const __hip_bfloat16*)p)[i])
              : ((const float*)p)[i];
}
__device__ __forceinline__ unsigned short bfbits(float f) {
  __hip_bfloat16 h = __float2bfloat16(f);
  union { __hip_bfloat16 h; unsigned short s; } u{h};
  return u.s;
}
__device__ __forceinline__ unsigned int pack2(float a, float b) {
  return ((unsigned int)bfbits(b) << 16) | bfbits(a);
}

template <int CTRL>
__device__ __forceinline__ float dppf(float v) {
  return __int_as_float(
      __builtin_amdgcn_update_dpp(0, __float_as_int(v), CTRL, 0xF, 0xF, false));
}

// ---------------- dtype detection + DPP direction probe ----------------
__global__ void k_detect(const void* emb, int n, int* flag) {
  __shared__ int s_big;
  if (threadIdx.x == 0) s_big = 0;
  __syncthreads();
  const __hip_bfloat16* p = (const __hip_bfloat16*)emb;
  int big = 0;
  for (int i = threadIdx.x; i < n; i += blockDim.x) {
    float v = __bfloat162float(p[i]);
    if (fabsf(v) > 1e4f) big = 1;
  }
  if (big) atomicOr(&s_big, 1);
  int lane = threadIdx.x & 63;
  int r = __builtin_amdgcn_update_dpp(0, lane, 0x124, 0xF, 0xF, false); // row_ror:4
  if (threadIdx.x == 5) flag[1] = (r == 9) ? 1 : 0;
  __syncthreads();
  if (threadIdx.x == 0) *flag = s_big ? 0 : 1;
}

// ---------------- embedding gather (emit bf16 X) ----------------
__global__ __launch_bounds__(64) void k_gather(const int* __restrict__ sent,
                                               const void* emb,
                                               __hip_bfloat16* __restrict__ X,
                                               const int* flagp) {
  int row = blockIdx.x;            // b*T + t
  int isbf = *flagp;
  long tok = (long)sent[row];
  long src = tok * ND;
  int d0 = threadIdx.x * 4;
  uint2 packed;
  packed.x = pack2(ldf(emb, isbf, src + d0 + 0), ldf(emb, isbf, src + d0 + 1));
  packed.y = pack2(ldf(emb, isbf, src + d0 + 2), ldf(emb, isbf, src + d0 + 3));
  *(uint2*)&X[(long)row * ND + d0] = packed;
}

// ---------------- MFMA GEMM: Y = Xbf @ W^T + b ----------------
// storeAttn=1: z<2 -> bf16 [bh][t][64] (Q,K); z==2 -> bf16 [bh][64][t] (V^T).
// storeAttn=0: f32 row-major [row][256].
__global__ __launch_bounds__(256) void k_gemm(
    const __hip_bfloat16* __restrict__ A, const void* W0, const void* W1,
    const void* W2, const void* B0, const void* B1, const void* B2,
    void* O0, void* O1, void* O2, const int* flagp, int storeAttn) {
  __shared__ __align__(16) unsigned short Abuf[64 * 32];
  __shared__ __align__(16) unsigned short Bbuf[64 * 32];
  int isbf = *flagp;
  int z = blockIdx.z;
  const void* W = (z == 0) ? W0 : (z == 1) ? W1 : W2;
  const void* Bb = (z == 0) ? B0 : (z == 1) ? B1 : B2;
  void* O = (z == 0) ? O0 : (z == 1) ? O1 : O2;

  int tid = threadIdx.x;
  int rowbase = blockIdx.x * 64;
  int colbase = blockIdx.y * 64;
  int srow = tid >> 2;             // 0..63
  int skq = (tid & 3) * 8;         // 0,8,16,24

  int wave = tid >> 6, lane = tid & 63;
  int li = lane & 15, quad = lane >> 4;
  int msub = (wave & 1) * 32, nsub = (wave >> 1) * 32;

  f32x4 acc[2][2];
#pragma unroll
  for (int i = 0; i < 2; ++i)
#pragma unroll
    for (int j = 0; j < 2; ++j) acc[i][j] = (f32x4){0.f, 0.f, 0.f, 0.f};

  for (int k0 = 0; k0 < 256; k0 += 32) {
    *(uint4*)&Abuf[srow * 32 + skq] =
        *(const uint4*)&A[(long)(rowbase + srow) * 256 + k0 + skq];
    long wb = (long)(colbase + srow) * 256 + k0 + skq;
    if (isbf) {
      *(uint4*)&Bbuf[srow * 32 + skq] = *(const uint4*)((const __hip_bfloat16*)W + wb);
    } else {
      const float* Wf = (const float*)W + wb;
      float4 lo = *(const float4*)Wf;
      float4 hi = *(const float4*)(Wf + 4);
      uint4 pk;
      pk.x = pack2(lo.x, lo.y); pk.y = pack2(lo.z, lo.w);
      pk.z = pack2(hi.x, hi.y); pk.w = pack2(hi.z, hi.w);
      *(uint4*)&Bbuf[srow * 32 + skq] = pk;
    }
    __syncthreads();

    LdsVec a0, a1, b0, b1;
    a0.u = *(const uint4*)&Abuf[(msub + li) * 32 + quad * 8];
    a1.u = *(const uint4*)&Abuf[(msub + 16 + li) * 32 + quad * 8];
    b0.u = *(const uint4*)&Bbuf[(nsub + li) * 32 + quad * 8];
    b1.u = *(const uint4*)&Bbuf[(nsub + 16 + li) * 32 + quad * 8];
    acc[0][0] = __builtin_amdgcn_mfma_f32_16x16x32_bf16(a0.v, b0.v, acc[0][0], 0, 0, 0);
    acc[0][1] = __builtin_amdgcn_mfma_f32_16x16x32_bf16(a0.v, b1.v, acc[0][1], 0, 0, 0);
    acc[1][0] = __builtin_amdgcn_mfma_f32_16x16x32_bf16(a1.v, b0.v, acc[1][0], 0, 0, 0);
    acc[1][1] = __builtin_amdgcn_mfma_f32_16x16x32_bf16(a1.v, b1.v, acc[1][1], 0, 0, 0);
    __syncthreads();
  }

#pragma unroll
  for (int nt = 0; nt < 2; ++nt) {
    int col = colbase + nsub + nt * 16 + li;
    float bias = ldf(Bb, isbf, col);
#pragma unroll
    for (int mt = 0; mt < 2; ++mt) {
#pragma unroll
      for (int reg = 0; reg < 4; ++reg) {
        int row = rowbase + msub + mt * 16 + quad * 4 + reg;
        float v = acc[mt][nt][reg] + bias;
        if (storeAttn) {
          int bb = row >> 9, tt = row & 511;
          int h = col >> 6, hd = col & 63;
          __hip_bfloat16 hv = __float2bfloat16(v);
          if (z == 2)
            ((__hip_bfloat16*)O)[((long)(bb * 4 + h) * 64 + hd) * 512 + tt] = hv;
          else
            ((__hip_bfloat16*)O)[((long)(bb * 4 + h) * 512 + tt) * 64 + hd] = hv;
        } else {
          ((float*)O)[(long)row * 256 + col] = v;
        }
      }
    }
  }
}

// ---------------- MFMA flash attention ----------------
// grid (64 bh, 8 qt), 256 thr = 4 waves; wave owns 16 Q-rows.
// Q,K: bf16 [bh][t][64]; Vt: bf16 [bh][64][t]. AO: bf16 [b*T+t][256].
#define LSTR 72
__global__ __launch_bounds__(256) void k_attn(const __hip_bfloat16* __restrict__ Qg,
                                              const __hip_bfloat16* __restrict__ Kg,
                                              const __hip_bfloat16* __restrict__ Vtg,
                                              __hip_bfloat16* __restrict__ AO) {
  __shared__ __align__(16) unsigned short Qs[64 * LSTR];
  __shared__ __align__(16) unsigned short Ks[64 * LSTR];
  __shared__ __align__(16) unsigned short Vts[64 * LSTR];
  __shared__ __align__(16) unsigned short Ps[64 * LSTR];
  int tid = threadIdx.x;
  int bh = blockIdx.x, qt = blockIdx.y;
  int wave = tid >> 6, lane = tid & 63, li = lane & 15, quad = lane >> 4;

  const __hip_bfloat16* Qb = Qg + ((long)bh * 512 + qt * 64) * 64;
#pragma unroll
  for (int c = 0; c < 2; ++c) {
    int idx = tid + c * 256;
    int r = idx >> 3, c8 = (idx & 7) * 8;
    *(uint4*)&Qs[r * LSTR + c8] = *(const uint4*)&Qb[(long)r * 64 + c8];
  }

  f32x4 accO[4];
  float mrow[4], lrow[4];
#pragma unroll
  for (int i = 0; i < 4; ++i) {
    accO[i] = (f32x4){0.f, 0.f, 0.f, 0.f};
    mrow[i] = -1e30f; lrow[i] = 0.f;
  }

  for (int kt = 0; kt < 8; ++kt) {
    __syncthreads();   // prev PV done + (kt=0) Qs staged
    const __hip_bfloat16* Kb = Kg + ((long)bh * 512 + kt * 64) * 64;
#pragma unroll
    for (int c = 0; c < 2; ++c) {
      int idx = tid + c * 256;
      int r = idx >> 3, c8 = (idx & 7) * 8;
      *(uint4*)&Ks[r * LSTR + c8] = *(const uint4*)&Kb[(long)r * 64 + c8];
      *(uint4*)&Vts[r * LSTR + c8] =
          *(const uint4*)&Vtg[((long)bh * 64 + r) * 512 + kt * 64 + c8];
    }
    __syncthreads();

    f32x4 s[4];
#pragma unroll
    for (int nb = 0; nb < 4; ++nb) s[nb] = (f32x4){0.f, 0.f, 0.f, 0.f};
#pragma unroll
    for (int nb = 0; nb < 4; ++nb)
#pragma unroll
      for (int kc = 0; kc < 2; ++kc) {
        LdsVec a, b;
        a.u = *(const uint4*)&Qs[(wave * 16 + li) * LSTR + kc * 32 + quad * 8];
        b.u = *(const uint4*)&Ks[(nb * 16 + li) * LSTR + kc * 32 + quad * 8];
        s[nb] = __builtin_amdgcn_mfma_f32_16x16x32_bf16(a.v, b.v, s[nb], 0, 0, 0);
      }
#pragma unroll
    for (int nb = 0; nb < 4; ++nb) s[nb] *= 0.125f;

#pragma unroll
    for (int reg = 0; reg < 4; ++reg) {
      float rm = fmaxf(fmaxf(s[0][reg], s[1][reg]), fmaxf(s[2][reg], s[3][reg]));
      rm = fmaxf(rm, __shfl_xor(rm, 1));
      rm = fmaxf(rm, __shfl_xor(rm, 2));
      rm = fmaxf(rm, __shfl_xor(rm, 4));
      rm = fmaxf(rm, __shfl_xor(rm, 8));
      float mnew = fmaxf(mrow[reg], rm);
      float alpha = __expf(mrow[reg] - mnew);
      mrow[reg] = mnew;
      float psum = 0.f;
#pragma unroll
      for (int nb = 0; nb < 4; ++nb) {
        float p = __expf(s[nb][reg] - mnew);
        psum += p;
        Ps[(wave * 16 + quad * 4 + reg) * LSTR + nb * 16 + li] =
            bfbits(p);
      }
      psum += __shfl_xor(psum, 1);
      psum += __shfl_xor(psum, 2);
      psum += __shfl_xor(psum, 4);
      psum += __shfl_xor(psum, 8);
      lrow[reg] = lrow[reg] * alpha + psum;
#pragma unroll
      for (int db = 0; db < 4; ++db) accO[db][reg] *= alpha;
    }
    __syncthreads();   // P visible to all lanes

#pragma unroll
    for (int db = 0; db < 4; ++db)
#pragma unroll
      for (int kc = 0; kc < 2; ++kc) {
        LdsVec a, b;
        a.u = *(const uint4*)&Ps[(wave * 16 + li) * LSTR + kc * 32 + quad * 8];
        b.u = *(const uint4*)&Vts[(db * 16 + li) * LSTR + kc * 32 + quad * 8];
        accO[db] = __builtin_amdgcn_mfma_f32_16x16x32_bf16(a.v, b.v, accO[db], 0, 0, 0);
      }
  }

  int b = bh >> 2, h = bh & 3;
#pragma unroll
  for (int reg = 0; reg < 4; ++reg) {
    float inv = 1.f / lrow[reg];
    int row = qt * 64 + wave * 16 + quad * 4 + reg;
#pragma unroll
    for (int db = 0; db < 4; ++db)
      AO[((long)(b * 512 + row)) * 256 + h * 64 + db * 16 + li] =
          __float2bfloat16(accO[db][reg] * inv);
  }
}

// ---------------- gate-angle precompute ----------------
// P2[x][t][64] with x = b>>2, col = (b&3)*16 + gate*4 + wire.
__global__ __launch_bounds__(256) void k_precomp(
    const float* __restrict__ ATTN, const void* Wf, const void* Wi,
    const void* Wg, const void* Wo2, const void* bF, const void* bI,
    const void* bG, const void* bO, const void* thF, const void* thI,
    const void* thG, const void* thO, float* __restrict__ P,
    const int* flagp) {
  __shared__ __align__(16) float Xs[16][260];
  __shared__ float Ws[16][260];
  __shared__ float ab[16];
  int isbf = *flagp;
  int tid = threadIdx.x;
  int r0 = blockIdx.x * 16;

#pragma unroll
  for (int c = 0; c < 4; ++c) {
    int fi = tid + c * 256;
    int r = fi >> 6, dq = (fi & 63) << 2;
    *(float4*)&Xs[r][dq] = *(const float4*)&ATTN[(long)(r0 + r) * 256 + dq];
  }
  for (int e = tid; e < 4096; e += 256) {
    int out = e >> 8, k = e & 255;
    int gate = out >> 2, w = out & 3;
    const void* Wsel = (gate == 0) ? Wf : (gate == 1) ? Wi : (gate == 2) ? Wg : Wo2;
    Ws[out][k] = ldf(Wsel, isbf, (long)w * 260 + k);
  }
  if (tid < 16) {
    int gate = tid >> 2, w = tid & 3;
    const void* bsel = (gate == 0) ? bF : (gate == 1) ? bI : (gate == 2) ? bG : bO;
    const void* tsel = (gate == 0) ? thF : (gate == 1) ? thI : (gate == 2) ? thG : thO;
    ab[tid] = ldf(bsel, isbf, w) + ldf(tsel, isbf, w);
  }
  __syncthreads();

  int r = tid >> 4, oi = tid & 15;
  float acc = ab[oi];
#pragma unroll 8
  for (int k = 0; k < 256; ++k) acc += Xs[r][k] * Ws[oi][k];
  int rg = r0 + r;
  int b = rg >> 9, t = rg & 511;
  P[(long)(b >> 2) * 32768 + (long)t * 64 + (b & 3) * 16 + oi] = acc;
}

// ---------------- sequential scan + DVFS heater ----------------
// blocks 0..3: real scan (identical to R4). blocks 4..255: fixed-length
// dependent-FMA heater (~27us @2.4GHz) to keep the clock domain busy —
// A/B test of the clock-droop theory for the scan's 875 cyc/step anomaly.
__global__ __launch_bounds__(64) void k_scan(const float* __restrict__ P,
                                             const void* Wf, const void* Wi,
                                             const void* Wg, const void* Wo2,
                                             float* __restrict__ HS,
                                             const int* flagp) {
  if (blockIdx.x >= 4) {
    float x = (float)(threadIdx.x + 1) * 1e-9f;
    for (int i = 0; i < 16000; ++i) x = __builtin_fmaf(x, 1.0000001f, 1e-9f);
    if (x == 123.456f) HS[32768 + threadIdx.x] = x;  // never true; defeats DCE
    return;
  }
  __shared__ __align__(16) float pb[2][2048];
  __shared__ __align__(16) float hsb[512 * 16];
  int lane = threadIdx.x;
  int q = lane >> 4, G = (lane >> 2) & 3, w = lane & 3;
  int isbf = flagp[0];
  int dir = flagp[1];
  const void* Wsel = (G == 0) ? Wf : (G == 1) ? Wi : (G == 2) ? Wg : Wo2;
  float r0 = ldf(Wsel, isbf, (long)w * 260 + 256 + 0);
  float r1 = ldf(Wsel, isbf, (long)w * 260 + 256 + 1);
  float r2 = ldf(Wsel, isbf, (long)w * 260 + 256 + 2);
  float r3 = ldf(Wsel, isbf, (long)w * 260 + 256 + 3);
  float kk = (G == 2) ? 2.f : 1.f;
  float km1 = kk - 1.f;
  int s0 = (0 - G) & 3, s1 = (1 - G) & 3, s2 = (2 - G) & 3, s3 = (3 - G) & 3;
  float h0 = 0.f, h1 = 0.f, h2 = 0.f, h3 = 0.f, cx = 0.f;
  int hoff = q * 4 + w;

  const float4* Pq = (const float4*)(P + (long)blockIdx.x * 32768);
  float4 stage[8];
#pragma unroll
  for (int j = 0; j < 8; ++j) stage[j] = Pq[j * 64 + lane];
#pragma unroll
  for (int j = 0; j < 8; ++j)
    *(float4*)&pb[0][(j * 64 + lane) * 4] = stage[j];
#pragma unroll
  for (int j = 0; j < 8; ++j) stage[j] = Pq[512 + j * 64 + lane];

  for (int ck = 0; ck < 16; ++ck) {
    const float* cur = pb[ck & 1];
    float lbuf[4];
#pragma unroll
    for (int j = 0; j < 4; ++j) lbuf[j] = cur[j * 64 + lane];
    int tbase = ck * 32;
    for (int tl = 0; tl < 32; tl += 4) {
#pragma unroll
      for (int u = 0; u < 4; ++u) {
        int t = tbase + tl + u;
        float pc = lbuf[u];
        lbuf[u] = cur[((tl + u + 4) & 31) * 64 + lane];
        float a = pc + r0 * h0 + r1 * h1 + r2 * h2 + r3 * h3;
        float c = __cosf(a);
        float c0 = dppf<0x00>(c), c1 = dppf<0x55>(c);
        float c2 = dppf<0xAA>(c), c3 = dppf<0xFF>(c);
        float p01 = c0 * c1, z23 = c2 * c3;
        float v = (w == 0) ? c1 * z23 : (w == 1) ? p01
                : (w == 2) ? p01 * c2 : p01 * z23;
        float val = kk / (1.f + __expf(-kk * v)) - km1;
        float ra = dppf<0x124>(val);
        float rb = dppf<0x128>(val);
        float rc = dppf<0x12C>(val);
        float rot1 = dir ? ra : rc;
        float rot3 = dir ? rc : ra;
        float f = (s0 == 0) ? val : (s0 == 1) ? rot1 : (s0 == 2) ? rb : rot3;
        float i = (s1 == 0) ? val : (s1 == 1) ? rot1 : (s1 == 2) ? rb : rot3;
        float g = (s2 == 0) ? val : (s2 == 1) ? rot1 : (s2 == 2) ? rb : rot3;
        float o = (s3 == 0) ? val : (s3 == 1) ? rot1 : (s3 == 2) ? rb : rot3;
        cx = f * cx + i * g;
        float th = 2.f / (1.f + __expf(-2.f * cx)) - 1.f;
        float hx = o * th;
        h0 = dppf<0x00>(hx); h1 = dppf<0x55>(hx);
        h2 = dppf<0xAA>(hx); h3 = dppf<0xFF>(hx);
        if (G == 0) hsb[t * 16 + hoff] = hx;
      }
    }
    if (ck < 15) {
#pragma unroll
      for (int j = 0; j < 8; ++j)
        *(float4*)&pb[(ck + 1) & 1][(j * 64 + lane) * 4] = stage[j];
      if (ck < 14) {
#pragma unroll
        for (int j = 0; j < 8; ++j)
          stage[j] = Pq[(ck + 2) * 512 + j * 64 + lane];
      }
    }
  }
  int hb = blockIdx.x * 16;
#pragma unroll
  for (int i4 = 0; i4 < 32; ++i4) {
    int fi = (i4 * 64 + lane) * 4;
    int t = fi >> 4, j = fi & 15;
    *(float4*)&HS[t * 64 + hb + j] = *(const float4*)&hsb[fi];
  }
}

// ---------------- logits + log_softmax ----------------
__global__ __launch_bounds__(64) void k_final(const float* __restrict__ HS,
                                              const void* Wt, const void* Bt,
                                              void* outp, const int* flagp) {
  int r = blockIdx.x;
  int b = r >> 9, t = r & 511;
  int j = threadIdx.x;
  int isbf = *flagp;
  const float* h = &HS[t * 64 + b * 4];
  float h0 = h[0], h1 = h[1], h2 = h[2], h3 = h[3];
  float lg = ldf(Bt, isbf, j)
           + h0 * ldf(Wt, isbf, (long)j * 4 + 0)
           + h1 * ldf(Wt, isbf, (long)j * 4 + 1)
           + h2 * ldf(Wt, isbf, (long)j * 4 + 2)
           + h3 * ldf(Wt, isbf, (long)j * 4 + 3);
  float mx = lg;
#pragma unroll
  for (int off = 1; off < 64; off <<= 1) mx = fmaxf(mx, __shfl_xor(mx, off));
  float e = __expf(lg - mx);
  float ssum = e;
#pragma unroll
  for (int off = 1; off < 64; off <<= 1) ssum += __shfl_xor(ssum, off);
  float res = lg - mx - __logf(ssum);
  long oidx = (long)r * 64 + j;
  if (isbf) ((__hip_bfloat16*)outp)[oidx] = __float2bfloat16(res);
  else ((float*)outp)[oidx] = res;
}

extern "C" void kernel_launch(void* const* d_in, const int* in_sizes, int n_in,
                              void* d_out, int out_size, void* d_ws, size_t ws_size,
                              hipStream_t stream) {
  const int* sent = (const int*)d_in[0];
  const void* emb = d_in[1];
  const void* Wq = d_in[2];  const void* bq = d_in[3];
  const void* Wk = d_in[4];  const void* bk = d_in[5];
  const void* Wv = d_in[6];  const void* bv = d_in[7];
  const void* Wo = d_in[8];  const void* bo = d_in[9];
  const void* Wf = d_in[10]; const void* bF = d_in[11]; const void* thF = d_in[12];
  const void* Wi = d_in[13]; const void* bI = d_in[14]; const void* thI = d_in[15];
  const void* Wg = d_in[16]; const void* bG = d_in[17]; const void* thG = d_in[18];
  const void* Wo2 = d_in[19]; const void* bO = d_in[20]; const void* thO = d_in[21];
  const void* Wt = d_in[22]; const void* Bt = d_in[23];

  int* flag = (int*)d_ws;
  float* base = (float*)((char*)d_ws + 256);
  __hip_bfloat16* Xbf  = (__hip_bfloat16*)base;              // 4MB; reused as AO
  __hip_bfloat16* Qbf  = (__hip_bfloat16*)(base + 1048576);  // 4MB
  __hip_bfloat16* Kbf  = (__hip_bfloat16*)(base + 2097152);  // 4MB
  __hip_bfloat16* Vtbf = (__hip_bfloat16*)(base + 3145728);  // 4MB
  float* ATTN = base + 1048576;     // 8MB f32, overlays dead Q/K
  float* Pp   = base + 4194304;     // 131072 floats (4 x 32768 block-major)
  float* HS   = Pp + 131072;        // 32768 floats + heater scrap

  k_detect<<<1, 256, 0, stream>>>(emb, 32768, flag);
  k_gather<<<8192, 64, 0, stream>>>(sent, emb, Xbf, flag);
  dim3 gq(128, 4, 3);
  k_gemm<<<gq, 256, 0, stream>>>(Xbf, Wq, Wk, Wv, bq, bk, bv,
                                 Qbf, Kbf, Vtbf, flag, 1);
  dim3 ga(64, 8, 1);
  k_attn<<<ga, 256, 0, stream>>>(Qbf, Kbf, Vtbf, Xbf);   // AO (bf16) -> Xbf
  dim3 gw(128, 4, 1);
  k_gemm<<<gw, 256, 0, stream>>>(Xbf, Wo, Wo, Wo, bo, bo, bo,
                                 ATTN, ATTN, ATTN, flag, 0);
  k_precomp<<<512, 256, 0, stream>>>(ATTN, Wf, Wi, Wg, Wo2, bF, bI, bG, bO,
                                     thF, thI, thG, thO, Pp, flag);
  k_scan<<<256, 64, 0, stream>>>(Pp, Wf, Wi, Wg, Wo2, HS, flag);
  k_final<<<8192, 64, 0, stream>>>(HS, Wt, Bt, d_out, flag);
}